// Round 1
// baseline (410.951 us; speedup 1.0000x reference)
//
#include <hip/hip_runtime.h>
#include <hip/hip_bf16.h>

#define NB 8192     // batch rows
#define SS 64       // seq
#define HH 768      // hidden
#define EE 5        // experts
#define LL 2        // labels

#define BM 32
#define BN 384
#define KT 32
#define NTHREADS 256

// K1: fused  g=relu(cls@W1+b1) -> partial logits = g@W2  (per N-half),
//     plus all_logits = cls.We + be   (computed by nh==0 blocks)
__global__ __launch_bounds__(NTHREADS, 2)
void k1_gemm(const float* __restrict__ hs, const float* __restrict__ W1,
             const float* __restrict__ b1, const float* __restrict__ W2,
             const float* __restrict__ We, const float* __restrict__ be,
             float* __restrict__ wsL, float* __restrict__ wsA)
{
    __shared__ float As[BM][KT + 4];   // +4 pad keeps float4 alignment & spreads banks
    __shared__ float Bs[KT][BN];

    const int bid = blockIdx.x;
    const int rb  = bid >> 1;          // row block 0..255
    const int nh  = bid & 1;           // N half 0/1
    const int r0  = rb * BM;
    const int n0  = nh * BN;
    const int tid = threadIdx.x;
    const int tx  = tid & 15;          // 16 col-groups
    const int ty  = tid >> 4;          // 16 row-pairs

    float acc[2][24];
    #pragma unroll
    for (int r = 0; r < 2; ++r)
        #pragma unroll
        for (int i = 0; i < 24; ++i) acc[r][i] = 0.f;

    // A staging: 32 rows x 32 k = 256 float4; one per thread
    const int arow = tid >> 3;            // 0..31
    const int akq  = (tid & 7) << 2;      // 0,4,...,28
    const float* aptr = hs + (size_t)(r0 + arow) * (SS * HH) + akq;

    for (int kt = 0; kt < HH; kt += KT) {
        // ---- stage A tile (cls rows) ----
        float4 av = *(const float4*)(aptr + kt);
        *(float4*)&As[arow][akq] = av;
        // ---- stage B tile (W1) : 32 x 384 = 3072 float4, 12 per thread ----
        #pragma unroll
        for (int j = 0; j < 12; ++j) {
            int f4i  = j * NTHREADS + tid;
            int brow = f4i / 96;              // BN/4 = 96
            int bc4  = (f4i % 96) << 2;
            float4 bv = *(const float4*)(W1 + (size_t)(kt + brow) * HH + n0 + bc4);
            *(float4*)&Bs[brow][bc4] = bv;
        }
        __syncthreads();

        #pragma unroll
        for (int k = 0; k < KT; ++k) {
            float a0 = As[2 * ty + 0][k];
            float a1 = As[2 * ty + 1][k];
            #pragma unroll
            for (int cg = 0; cg < 6; ++cg) {
                float4 bv = *(float4*)&Bs[k][cg * 64 + tx * 4];
                acc[0][cg * 4 + 0] += a0 * bv.x;
                acc[0][cg * 4 + 1] += a0 * bv.y;
                acc[0][cg * 4 + 2] += a0 * bv.z;
                acc[0][cg * 4 + 3] += a0 * bv.w;
                acc[1][cg * 4 + 0] += a1 * bv.x;
                acc[1][cg * 4 + 1] += a1 * bv.y;
                acc[1][cg * 4 + 2] += a1 * bv.z;
                acc[1][cg * 4 + 3] += a1 * bv.w;
            }
        }
        __syncthreads();
    }

    // ---- bias + relu + @W2 partial logits (this N-half) ----
    float lacc[2][EE];
    #pragma unroll
    for (int r = 0; r < 2; ++r)
        #pragma unroll
        for (int e = 0; e < EE; ++e) lacc[r][e] = 0.f;

    #pragma unroll
    for (int cg = 0; cg < 6; ++cg) {
        int cbase = n0 + cg * 64 + tx * 4;
        float4 bb = *(const float4*)(b1 + cbase);
        float bbs[4] = {bb.x, bb.y, bb.z, bb.w};
        #pragma unroll
        for (int i = 0; i < 4; ++i) {
            int c = cbase + i;
            float g0 = acc[0][cg * 4 + i] + bbs[i]; g0 = g0 > 0.f ? g0 : 0.f;
            float g1 = acc[1][cg * 4 + i] + bbs[i]; g1 = g1 > 0.f ? g1 : 0.f;
            #pragma unroll
            for (int e = 0; e < EE; ++e) {
                float w = W2[c * EE + e];
                lacc[0][e] += g0 * w;
                lacc[1][e] += g1 * w;
            }
        }
    }
    // reduce across the 16 tx lanes (they are consecutive lanes within a wave)
    #pragma unroll
    for (int r = 0; r < 2; ++r) {
        #pragma unroll
        for (int e = 0; e < EE; ++e) {
            float v = lacc[r][e];
            v += __shfl_xor(v, 1);
            v += __shfl_xor(v, 2);
            v += __shfl_xor(v, 4);
            v += __shfl_xor(v, 8);
            if (tx == 0)
                wsL[((size_t)nh * NB + r0 + 2 * ty + r) * EE + e] = v;
        }
    }

    // ---- all_logits = cls . We + be   (only nh==0 blocks; 320 dots of len 768) ----
    if (nh == 0) {
        for (int t = tid; t < BM * EE * LL; t += NTHREADS) {
            int row = t / (EE * LL);
            int el  = t % (EE * LL);
            int e = el >> 1, l = el & 1;
            const float* cp = hs + (size_t)(r0 + row) * (SS * HH);
            const float* wp = We + e * (HH * LL) + l;
            float s0 = 0.f, s1 = 0.f, s2 = 0.f, s3 = 0.f;
            for (int h = 0; h < HH; h += 4) {
                float4 cv = *(const float4*)(cp + h);
                s0 += cv.x * wp[2 * h + 0];
                s1 += cv.y * wp[2 * h + 2];
                s2 += cv.z * wp[2 * h + 4];
                s3 += cv.w * wp[2 * h + 6];
            }
            wsA[(size_t)(r0 + row) * (EE * LL) + el] = (s0 + s1) + (s2 + s3) + be[el];
        }
    }
}

// K2: per-row softmax, top-2 (lowest-index tie-break like lax.top_k), outputs
__global__ __launch_bounds__(256)
void k2_epilogue(const float* __restrict__ wsL, const float* __restrict__ wsA,
                 const float* __restrict__ b2, float* __restrict__ out)
{
    int row = blockIdx.x * 256 + threadIdx.x;
    if (row >= NB) return;

    float lg[EE];
    #pragma unroll
    for (int e = 0; e < EE; ++e)
        lg[e] = wsL[(size_t)row * EE + e] + wsL[((size_t)NB + row) * EE + e] + b2[e];

    float m = lg[0];
    #pragma unroll
    for (int e = 1; e < EE; ++e) m = fmaxf(m, lg[e]);
    float p[EE]; float sum = 0.f;
    #pragma unroll
    for (int e = 0; e < EE; ++e) { p[e] = expf(lg[e] - m); sum += p[e]; }
    float inv = 1.f / sum;
    #pragma unroll
    for (int e = 0; e < EE; ++e) p[e] *= inv;

    // gating_probs
    #pragma unroll
    for (int e = 0; e < EE; ++e)
        out[(size_t)NB * LL + (size_t)row * EE + e] = p[e];

    // top-2 with lowest-index tie-break (strict > while scanning ascending)
    int i1 = 0; float v1 = p[0];
    #pragma unroll
    for (int e = 1; e < EE; ++e) if (p[e] > v1) { v1 = p[e]; i1 = e; }
    int i2 = -1; float v2 = -1.f;
    #pragma unroll
    for (int e = 0; e < EE; ++e) if (e != i1 && p[e] > v2) { v2 = p[e]; i2 = e; }

    float wsum = v1 + v2;
    float w1n = v1 / wsum, w2n = v2 / wsum;

    float a[EE * LL];
    #pragma unroll
    for (int el = 0; el < EE * LL; ++el) a[el] = wsA[(size_t)row * (EE * LL) + el];

    // final_logits
    #pragma unroll
    for (int l = 0; l < LL; ++l)
        out[(size_t)row * LL + l] = w1n * a[i1 * LL + l] + w2n * a[i2 * LL + l];

    // expert_logits (masked all_logits)
    #pragma unroll
    for (int e = 0; e < EE; ++e)
        #pragma unroll
        for (int l = 0; l < LL; ++l)
            out[(size_t)NB * (LL + EE) + (size_t)row * (EE * LL) + e * LL + l] =
                (e == i1 || e == i2) ? a[e * LL + l] : 0.f;
}

extern "C" void kernel_launch(void* const* d_in, const int* in_sizes, int n_in,
                              void* d_out, int out_size, void* d_ws, size_t ws_size,
                              hipStream_t stream)
{
    const float* hs = (const float*)d_in[0];
    const float* W1 = (const float*)d_in[1];
    const float* b1 = (const float*)d_in[2];
    const float* W2 = (const float*)d_in[3];
    const float* b2 = (const float*)d_in[4];
    const float* We = (const float*)d_in[5];
    const float* be = (const float*)d_in[6];
    float* out = (float*)d_out;

    float* wsL = (float*)d_ws;            // [2][8192][5] partial gating logits
    float* wsA = wsL + 2 * NB * EE;       // [8192][10]  all_logits (+be)

    hipLaunchKernelGGL(k1_gemm, dim3((NB / BM) * 2), dim3(NTHREADS), 0, stream,
                       hs, W1, b1, W2, We, be, wsL, wsA);
    hipLaunchKernelGGL(k2_epilogue, dim3(NB / 256), dim3(256), 0, stream,
                       wsL, wsA, b2, out);
}

// Round 2
// 207.344 us; speedup vs baseline: 1.9820x; 1.9820x over previous
//
#include <hip/hip_runtime.h>
#include <hip/hip_bf16.h>

#define NB 8192     // batch rows
#define SS 64       // seq
#define HH 768      // hidden
#define EE 5        // experts
#define LL 2        // labels

#define BMt 128
#define BNt 128
#define KT 32
#define NTH 256
#define NBLK_N 6    // 768/128
#define APAD 132    // padded A-tile row stride (words); 528B keeps float4 align

// ---------------- K1: cls@W1 + b1 -> relu -> @W2 partial gating logits ----------------
__global__ __launch_bounds__(NTH, 2)
void k1_gemm(const float* __restrict__ hs, const float* __restrict__ W1,
             const float* __restrict__ b1, const float* __restrict__ W2,
             float* __restrict__ wsL)
{
    __shared__ float As[KT][APAD];   // k-major (transposed)
    __shared__ float Bs[KT][BNt];

    const int bid = blockIdx.x;
    const int mb  = bid / NBLK_N;
    const int nb  = bid % NBLK_N;
    const int r0  = mb * BMt;
    const int n0  = nb * BNt;
    const int tid = threadIdx.x;
    const int tx  = tid & 15;        // col group (8 cols each)
    const int ty  = tid >> 4;        // row group (8 rows each)

    // staging decomposition
    const int aq   = tid & 7;        // k-quad within tile (fixed per thread)
    const int arow = tid >> 3;       // base row (0..31), +32*j
    const int brow = tid >> 5;       // base B row (0..7 step), +8*j
    const int bc4  = (tid & 31) << 2;

    float acc[8][8];
    #pragma unroll
    for (int i = 0; i < 8; ++i)
        #pragma unroll
        for (int j = 0; j < 8; ++j) acc[i][j] = 0.f;

    float4 pa[4], pb[4];

    // ---- load tile 0 into regs ----
    #pragma unroll
    for (int j = 0; j < 4; ++j) {
        pa[j] = *(const float4*)(hs + (size_t)(r0 + arow + 32 * j) * (SS * HH) + aq * 4);
        pb[j] = *(const float4*)(W1 + (size_t)(brow + 8 * j) * HH + n0 + bc4);
    }
    // ---- write tile 0 to LDS ----
    #pragma unroll
    for (int j = 0; j < 4; ++j) {
        As[aq * 4 + 0][arow + 32 * j] = pa[j].x;
        As[aq * 4 + 1][arow + 32 * j] = pa[j].y;
        As[aq * 4 + 2][arow + 32 * j] = pa[j].z;
        As[aq * 4 + 3][arow + 32 * j] = pa[j].w;
        *(float4*)&Bs[brow + 8 * j][bc4] = pb[j];
    }
    __syncthreads();

    for (int t = 0; t < HH / KT; ++t) {
        // prefetch next tile into regs (overlaps with compute below)
        if (t < HH / KT - 1) {
            const int kt = (t + 1) * KT;
            #pragma unroll
            for (int j = 0; j < 4; ++j) {
                pa[j] = *(const float4*)(hs + (size_t)(r0 + arow + 32 * j) * (SS * HH) + kt + aq * 4);
                pb[j] = *(const float4*)(W1 + (size_t)(kt + brow + 8 * j) * HH + n0 + bc4);
            }
        }
        // compute on current LDS tile
        #pragma unroll 4
        for (int k = 0; k < KT; ++k) {
            float4 a0 = *(float4*)&As[k][ty * 8];
            float4 a1 = *(float4*)&As[k][ty * 8 + 4];
            float4 b0 = *(float4*)&Bs[k][tx * 8];
            float4 b1v = *(float4*)&Bs[k][tx * 8 + 4];
            float ar[8] = {a0.x, a0.y, a0.z, a0.w, a1.x, a1.y, a1.z, a1.w};
            float br[8] = {b0.x, b0.y, b0.z, b0.w, b1v.x, b1v.y, b1v.z, b1v.w};
            #pragma unroll
            for (int i = 0; i < 8; ++i)
                #pragma unroll
                for (int j = 0; j < 8; ++j)
                    acc[i][j] += ar[i] * br[j];
        }
        __syncthreads();
        if (t < HH / KT - 1) {
            #pragma unroll
            for (int j = 0; j < 4; ++j) {
                As[aq * 4 + 0][arow + 32 * j] = pa[j].x;
                As[aq * 4 + 1][arow + 32 * j] = pa[j].y;
                As[aq * 4 + 2][arow + 32 * j] = pa[j].z;
                As[aq * 4 + 3][arow + 32 * j] = pa[j].w;
                *(float4*)&Bs[brow + 8 * j][bc4] = pb[j];
            }
            __syncthreads();
        }
    }

    // ---- epilogue: bias + relu + @W2 -> partial logits ----
    float lacc[8][EE];
    #pragma unroll
    for (int i = 0; i < 8; ++i)
        #pragma unroll
        for (int e = 0; e < EE; ++e) lacc[i][e] = 0.f;

    #pragma unroll
    for (int j = 0; j < 8; ++j) {
        const int c = n0 + tx * 8 + j;
        const float bb = b1[c];
        float w[EE];
        #pragma unroll
        for (int e = 0; e < EE; ++e) w[e] = W2[c * EE + e];
        #pragma unroll
        for (int i = 0; i < 8; ++i) {
            float g = acc[i][j] + bb;
            g = g > 0.f ? g : 0.f;
            #pragma unroll
            for (int e = 0; e < EE; ++e) lacc[i][e] += g * w[e];
        }
    }
    // reduce over the 16 tx lanes (lane bits 0..3)
    #pragma unroll
    for (int i = 0; i < 8; ++i) {
        #pragma unroll
        for (int e = 0; e < EE; ++e) {
            float v = lacc[i][e];
            v += __shfl_xor(v, 1);
            v += __shfl_xor(v, 2);
            v += __shfl_xor(v, 4);
            v += __shfl_xor(v, 8);
            if (tx == 0)
                wsL[((size_t)nb * NB + r0 + ty * 8 + i) * EE + e] = v;
        }
    }
}

// ---------------- K1b: all_logits = cls . We + be ----------------
__global__ __launch_bounds__(256)
void k1b_einsum(const float* __restrict__ hs, const float* __restrict__ We,
                const float* __restrict__ be, float* __restrict__ wsA)
{
    const int tid  = threadIdx.x;
    const int lane = tid & 7;       // k segment (96 each)
    const int rowi = tid >> 3;      // 0..31
    const size_t row = (size_t)blockIdx.x * 32 + rowi;
    const float* cp = hs + row * (SS * HH) + lane * 96;

    float acc[EE * LL];
    #pragma unroll
    for (int u = 0; u < EE * LL; ++u) acc[u] = 0.f;

    for (int k4 = 0; k4 < 96; k4 += 4) {
        float4 cv = *(const float4*)(cp + k4);
        const int kabs = lane * 96 + k4;
        #pragma unroll
        for (int e = 0; e < EE; ++e) {
            const float* wp = We + e * (HH * LL) + kabs * LL;
            float4 w01 = *(const float4*)(wp);       // (k,l0)(k,l1)(k+1,l0)(k+1,l1)
            float4 w23 = *(const float4*)(wp + 4);
            acc[e * 2 + 0] += cv.x * w01.x + cv.y * w01.z + cv.z * w23.x + cv.w * w23.z;
            acc[e * 2 + 1] += cv.x * w01.y + cv.y * w01.w + cv.z * w23.y + cv.w * w23.w;
        }
    }
    #pragma unroll
    for (int u = 0; u < EE * LL; ++u) {
        float v = acc[u];
        v += __shfl_xor(v, 1);
        v += __shfl_xor(v, 2);
        v += __shfl_xor(v, 4);
        acc[u] = v;
    }
    if (lane == 0) {
        #pragma unroll
        for (int u = 0; u < EE * LL; ++u)
            wsA[row * (EE * LL) + u] = acc[u] + be[u];
    }
}

// ---------------- K2: softmax, top-2, outputs ----------------
__global__ __launch_bounds__(256)
void k2_epilogue(const float* __restrict__ wsL, const float* __restrict__ wsA,
                 const float* __restrict__ b2, float* __restrict__ out)
{
    int row = blockIdx.x * 256 + threadIdx.x;
    if (row >= NB) return;

    float lg[EE];
    #pragma unroll
    for (int e = 0; e < EE; ++e) {
        float s = b2[e];
        #pragma unroll
        for (int p = 0; p < NBLK_N; ++p)
            s += wsL[((size_t)p * NB + row) * EE + e];
        lg[e] = s;
    }

    float m = lg[0];
    #pragma unroll
    for (int e = 1; e < EE; ++e) m = fmaxf(m, lg[e]);
    float p[EE]; float sum = 0.f;
    #pragma unroll
    for (int e = 0; e < EE; ++e) { p[e] = expf(lg[e] - m); sum += p[e]; }
    float inv = 1.f / sum;
    #pragma unroll
    for (int e = 0; e < EE; ++e) p[e] *= inv;

    // gating_probs
    #pragma unroll
    for (int e = 0; e < EE; ++e)
        out[(size_t)NB * LL + (size_t)row * EE + e] = p[e];

    // top-2, lowest-index tie-break (matches lax.top_k)
    int i1 = 0; float v1 = p[0];
    #pragma unroll
    for (int e = 1; e < EE; ++e) if (p[e] > v1) { v1 = p[e]; i1 = e; }
    int i2 = -1; float v2 = -1.f;
    #pragma unroll
    for (int e = 0; e < EE; ++e) if (e != i1 && p[e] > v2) { v2 = p[e]; i2 = e; }

    float wsum = v1 + v2;
    float w1n = v1 / wsum, w2n = v2 / wsum;

    float a[EE * LL];
    #pragma unroll
    for (int el = 0; el < EE * LL; ++el) a[el] = wsA[(size_t)row * (EE * LL) + el];

    // final_logits
    #pragma unroll
    for (int l = 0; l < LL; ++l)
        out[(size_t)row * LL + l] = w1n * a[i1 * LL + l] + w2n * a[i2 * LL + l];

    // expert_logits
    #pragma unroll
    for (int e = 0; e < EE; ++e)
        #pragma unroll
        for (int l = 0; l < LL; ++l)
            out[(size_t)NB * (LL + EE) + (size_t)row * (EE * LL) + e * LL + l] =
                (e == i1 || e == i2) ? a[e * LL + l] : 0.f;
}

extern "C" void kernel_launch(void* const* d_in, const int* in_sizes, int n_in,
                              void* d_out, int out_size, void* d_ws, size_t ws_size,
                              hipStream_t stream)
{
    const float* hs = (const float*)d_in[0];
    const float* W1 = (const float*)d_in[1];
    const float* b1 = (const float*)d_in[2];
    const float* W2 = (const float*)d_in[3];
    const float* b2 = (const float*)d_in[4];
    const float* We = (const float*)d_in[5];
    const float* be = (const float*)d_in[6];
    float* out = (float*)d_out;

    float* wsL = (float*)d_ws;                    // [6][8192][5] partial gating logits
    float* wsA = wsL + (size_t)NBLK_N * NB * EE;  // [8192][10]  all_logits (+be)

    hipLaunchKernelGGL(k1_gemm, dim3((NB / BMt) * NBLK_N), dim3(NTH), 0, stream,
                       hs, W1, b1, W2, wsL);
    hipLaunchKernelGGL(k1b_einsum, dim3(NB / 32), dim3(256), 0, stream,
                       hs, We, be, wsA);
    hipLaunchKernelGGL(k2_epilogue, dim3(NB / 256), dim3(256), 0, stream,
                       wsL, wsA, b2, out);
}

// Round 5
// 89.773 us; speedup vs baseline: 4.5777x; 2.3096x over previous
//
#include <hip/hip_runtime.h>
#include <hip/hip_bf16.h>

#define NB 8192
#define SS 64
#define HH 768
#define EE 5
#define LL 2

typedef _Float16 f16;
typedef f16 f16x8 __attribute__((ext_vector_type(8)));
typedef float f32x4 __attribute__((ext_vector_type(4)));

#define LO_SCALE 2048.0f
#define LO_INV   4.8828125e-4f   // 1/2048

// ---------------- K0: all_logits einsum  wsA[u][row] = cls . We + be ----------------
__global__ __launch_bounds__(256)
void k0_einsum(const float* __restrict__ hs, const float* __restrict__ We,
               const float* __restrict__ be, float* __restrict__ wsA)
{
    const int wid = threadIdx.x >> 6, lane = threadIdx.x & 63;
    const size_t row = (size_t)blockIdx.x * 4 + wid;
    const float* rp = hs + row * (SS * HH);
    const int kb = lane * 12;

    float4 va = *(const float4*)(rp + kb);
    float4 vb = *(const float4*)(rp + kb + 4);
    float4 vc = *(const float4*)(rp + kb + 8);
    float v[12] = {va.x, va.y, va.z, va.w, vb.x, vb.y, vb.z, vb.w, vc.x, vc.y, vc.z, vc.w};

    float acc[EE * LL];
    #pragma unroll
    for (int u = 0; u < EE * LL; ++u) acc[u] = 0.f;
    #pragma unroll
    for (int j = 0; j < 12; ++j) {
        float c = v[j];
        int h = kb + j;
        #pragma unroll
        for (int e = 0; e < EE; ++e) {
            float2 w = *(const float2*)(We + (size_t)e * (HH * LL) + h * 2);
            acc[2 * e]     += c * w.x;
            acc[2 * e + 1] += c * w.y;
        }
    }
    #pragma unroll
    for (int u = 0; u < EE * LL; ++u) {
        float s = acc[u];
        s += __shfl_xor(s, 1);  s += __shfl_xor(s, 2);  s += __shfl_xor(s, 4);
        s += __shfl_xor(s, 8);  s += __shfl_xor(s, 16); s += __shfl_xor(s, 32);
        if (lane == 0) wsA[(size_t)u * NB + row] = s + be[u];
    }
}

// ---------------- K0b: W1 -> transposed f16 hi/lo(x2048)  bT[n][k] = W1[k][n] ----------------
__global__ __launch_bounds__(256)
void k0b_convB(const float* __restrict__ W1, f16* __restrict__ bHi, f16* __restrict__ bLo)
{
    __shared__ float tile[64][65];
    const int kb = (blockIdx.x % 12) * 64, nb = (blockIdx.x / 12) * 64;
    const int tid = threadIdx.x;
    const int cc = tid & 63, rr = tid >> 6;
    #pragma unroll
    for (int i = 0; i < 16; ++i) {
        int r = i * 4 + rr;
        tile[r][cc] = W1[(size_t)(kb + r) * HH + nb + cc];
    }
    __syncthreads();
    const int n = tid >> 2, kc = (tid & 3) * 16;
    f16 hh[16], ll[16];
    #pragma unroll
    for (int j = 0; j < 16; ++j) {
        float x = tile[kc + j][n];
        f16 h = (f16)x;
        hh[j] = h;
        ll[j] = (f16)((x - (float)h) * LO_SCALE);
    }
    f16* dh = bHi + (size_t)(nb + n) * HH + kb + kc;
    f16* dl = bLo + (size_t)(nb + n) * HH + kb + kc;
    f16x8 t;
    t = (f16x8){hh[0],hh[1],hh[2],hh[3],hh[4],hh[5],hh[6],hh[7]};       *(f16x8*)(dh)     = t;
    t = (f16x8){hh[8],hh[9],hh[10],hh[11],hh[12],hh[13],hh[14],hh[15]}; *(f16x8*)(dh + 8) = t;
    t = (f16x8){ll[0],ll[1],ll[2],ll[3],ll[4],ll[5],ll[6],ll[7]};       *(f16x8*)(dl)     = t;
    t = (f16x8){ll[8],ll[9],ll[10],ll[11],ll[12],ll[13],ll[14],ll[15]}; *(f16x8*)(dl + 8) = t;
}

// ---------------- K1: MFMA GEMM, in-register f16 hi/lo split of A ----------------
// LDS 28 KB: aHi [0,8K) | aLo [8K,16K) | bHi [16K,22528) | bLo [22528,28672)
// row r at byte r*64 in its region; phys kseg slot s holds logical kseg s^((r>>1)&3)

__global__ __launch_bounds__(256, 2)
void k1_gemm(const float* __restrict__ hs, const f16* __restrict__ bHi,
             const f16* __restrict__ bLo, const float* __restrict__ b1,
             const float* __restrict__ W2, float* __restrict__ wsP)
{
    __shared__ alignas(16) char lds[28672];
    const int tid = threadIdx.x, wid = tid >> 6, lane = tid & 63;
    const int mb = blockIdx.x & 63, nb = blockIdx.x >> 6;   // bid%8 = mb%8 -> XCD grouping
    const int r0 = mb * 128, n0 = nb * 96;
    const int wm = wid >> 1, wn = wid & 1;

    f32x4 accH[4][3], accL[4][3];
    #pragma unroll
    for (int i = 0; i < 4; ++i)
        #pragma unroll
        for (int j = 0; j < 3; ++j) {
            accH[i][j] = (f32x4){0.f, 0.f, 0.f, 0.f};
            accL[i][j] = (f32x4){0.f, 0.f, 0.f, 0.f};
        }

    // ---- A staging: thread -> (row ar, k-half ah of 16 floats) ----
    const int ar = tid >> 1;
    const int ah = tid & 1;
    const float* ap = hs + (size_t)(r0 + ar) * (SS * HH) + ah * 16;
    const int as = (ar >> 1) & 3;
    const int aoff0 = ar * 64 + (((2 * ah + 0) ^ as) & 3) * 16;
    const int aoff1 = ar * 64 + (((2 * ah + 1) ^ as) & 3) * 16;

    // ---- B staging: 12 chunks of 1 KB; 3 per thread-quarter ----
    const f16* gptrB[3];
    int boff[3];
    #pragma unroll
    for (int j = 0; j < 3; ++j) {
        int q = j * 4 + wid;                         // 0..11
        const f16* base = (q < 6) ? bHi : bLo;
        int sr0 = ((q < 6) ? q : q - 6) * 16;
        int srow = sr0 + (lane >> 2);
        int ks = ((lane & 3) ^ (srow >> 1)) & 3;
        gptrB[j] = base + (size_t)(n0 + srow) * HH + ks * 8;
        boff[j]  = 16384 + q * 1024 + (lane >> 2) * 64 + (lane & 3) * 16;
    }

    float4 pa[4];
    f16x8 pb[3];
    #pragma unroll
    for (int j = 0; j < 4; ++j) pa[j] = *(const float4*)(ap + 4 * j);
    #pragma unroll
    for (int j = 0; j < 3; ++j) pb[j] = *(const f16x8*)(gptrB[j]);

    const int arow_base = wm * 64 + (lane & 15);
    const int bcol_base = wn * 48 + (lane & 15);
    const int lg = lane >> 4;

    for (int t = 0; t < 24; ++t) {
        __syncthreads();                      // previous compute done reading LDS
        // convert A to f16 hi / lo*2048 and write fragments
        {
            float u[16] = {pa[0].x, pa[0].y, pa[0].z, pa[0].w,
                           pa[1].x, pa[1].y, pa[1].z, pa[1].w,
                           pa[2].x, pa[2].y, pa[2].z, pa[2].w,
                           pa[3].x, pa[3].y, pa[3].z, pa[3].w};
            f16 hi[16], lo[16];
            #pragma unroll
            for (int i = 0; i < 16; ++i) {
                f16 h = (f16)u[i];
                hi[i] = h;
                lo[i] = (f16)((u[i] - (float)h) * LO_SCALE);
            }
            *(f16x8*)(lds + aoff0) = (f16x8){hi[0],hi[1],hi[2],hi[3],hi[4],hi[5],hi[6],hi[7]};
            *(f16x8*)(lds + aoff1) = (f16x8){hi[8],hi[9],hi[10],hi[11],hi[12],hi[13],hi[14],hi[15]};
            *(f16x8*)(lds + 8192 + aoff0) = (f16x8){lo[0],lo[1],lo[2],lo[3],lo[4],lo[5],lo[6],lo[7]};
            *(f16x8*)(lds + 8192 + aoff1) = (f16x8){lo[8],lo[9],lo[10],lo[11],lo[12],lo[13],lo[14],lo[15]};
        }
        #pragma unroll
        for (int j = 0; j < 3; ++j) *(f16x8*)(lds + boff[j]) = pb[j];
        __syncthreads();                      // staging visible

        if (t < 23) {                         // prefetch next tile (hides under MFMA)
            #pragma unroll
            for (int j = 0; j < 4; ++j) pa[j] = *(const float4*)(ap + (t + 1) * 32 + 4 * j);
            #pragma unroll
            for (int j = 0; j < 3; ++j) { gptrB[j] += 32; pb[j] = *(const f16x8*)(gptrB[j]); }
        }

        f16x8 af[4][2], bf[3][2];
        #pragma unroll
        for (int mf = 0; mf < 4; ++mf) {
            int srow = arow_base + mf * 16;
            int off = srow * 64 + (((lg ^ (srow >> 1)) & 3) << 4);
            af[mf][0] = *(const f16x8*)(lds + off);
            af[mf][1] = *(const f16x8*)(lds + 8192 + off);
        }
        #pragma unroll
        for (int nf = 0; nf < 3; ++nf) {
            int scol = bcol_base + nf * 16;
            int off = scol * 64 + (((lg ^ (scol >> 1)) & 3) << 4);
            bf[nf][0] = *(const f16x8*)(lds + 16384 + off);
            bf[nf][1] = *(const f16x8*)(lds + 22528 + off);
        }
        #pragma unroll
        for (int mf = 0; mf < 4; ++mf)
            #pragma unroll
            for (int nf = 0; nf < 3; ++nf) {
                accH[mf][nf] = __builtin_amdgcn_mfma_f32_16x16x32_f16(af[mf][0], bf[nf][0], accH[mf][nf], 0, 0, 0);
                accL[mf][nf] = __builtin_amdgcn_mfma_f32_16x16x32_f16(af[mf][0], bf[nf][1], accL[mf][nf], 0, 0, 0);
                accL[mf][nf] = __builtin_amdgcn_mfma_f32_16x16x32_f16(af[mf][1], bf[nf][0], accL[mf][nf], 0, 0, 0);
            }
    }

    // ---- epilogue: combine scales, bias + relu + @W2 partials ----
    float lacc[4][4][EE];
    #pragma unroll
    for (int mf = 0; mf < 4; ++mf)
        #pragma unroll
        for (int r = 0; r < 4; ++r)
            #pragma unroll
            for (int e = 0; e < EE; ++e) lacc[mf][r][e] = 0.f;

    #pragma unroll
    for (int nf = 0; nf < 3; ++nf) {
        int gc = n0 + wn * 48 + nf * 16 + (lane & 15);
        float bb = b1[gc];
        float w[EE];
        #pragma unroll
        for (int e = 0; e < EE; ++e) w[e] = W2[gc * EE + e];
        #pragma unroll
        for (int mf = 0; mf < 4; ++mf)
            #pragma unroll
            for (int r = 0; r < 4; ++r) {
                float g = accH[mf][nf][r] + LO_INV * accL[mf][nf][r] + bb;
                g = fmaxf(g, 0.f);
                #pragma unroll
                for (int e = 0; e < EE; ++e) lacc[mf][r][e] += g * w[e];
            }
    }
    #pragma unroll
    for (int mf = 0; mf < 4; ++mf)
        #pragma unroll
        for (int r = 0; r < 4; ++r)
            #pragma unroll
            for (int e = 0; e < EE; ++e) {
                float s = lacc[mf][r][e];
                s += __shfl_xor(s, 1); s += __shfl_xor(s, 2);
                s += __shfl_xor(s, 4); s += __shfl_xor(s, 8);
                lacc[mf][r][e] = s;
            }
    if ((lane & 15) == 0) {
        int rg = lane >> 4;
        int p = nb * 2 + wn;
        #pragma unroll
        for (int mf = 0; mf < 4; ++mf)
            #pragma unroll
            for (int r = 0; r < 4; ++r)
                #pragma unroll
                for (int e = 0; e < EE; ++e)
                    wsP[(size_t)(p * EE + e) * NB + r0 + wm * 64 + mf * 16 + rg * 4 + r] = lacc[mf][r][e];
    }
}

// ---------------- K2: softmax, top-2, outputs ----------------
__global__ __launch_bounds__(256)
void k2_epilogue(const float* __restrict__ wsP, const float* __restrict__ wsA,
                 const float* __restrict__ b2, float* __restrict__ out)
{
    int row = blockIdx.x * 256 + threadIdx.x;
    if (row >= NB) return;

    float lg[EE];
    #pragma unroll
    for (int e = 0; e < EE; ++e) {
        float s = b2[e];
        #pragma unroll
        for (int p = 0; p < 16; ++p)
            s += wsP[(size_t)(p * EE + e) * NB + row];
        lg[e] = s;
    }

    float m = lg[0];
    #pragma unroll
    for (int e = 1; e < EE; ++e) m = fmaxf(m, lg[e]);
    float pr[EE]; float sum = 0.f;
    #pragma unroll
    for (int e = 0; e < EE; ++e) { pr[e] = expf(lg[e] - m); sum += pr[e]; }
    float inv = 1.f / sum;
    #pragma unroll
    for (int e = 0; e < EE; ++e) pr[e] *= inv;

    #pragma unroll
    for (int e = 0; e < EE; ++e)
        out[(size_t)NB * LL + (size_t)row * EE + e] = pr[e];

    int i1 = 0; float v1 = pr[0];
    #pragma unroll
    for (int e = 1; e < EE; ++e) if (pr[e] > v1) { v1 = pr[e]; i1 = e; }
    int i2 = -1; float v2 = -1.f;
    #pragma unroll
    for (int e = 0; e < EE; ++e) if (e != i1 && pr[e] > v2) { v2 = pr[e]; i2 = e; }

    float wsum = v1 + v2;
    float w1n = v1 / wsum, w2n = v2 / wsum;

    float a[EE * LL];
    #pragma unroll
    for (int el = 0; el < EE * LL; ++el) a[el] = wsA[(size_t)el * NB + row];

    #pragma unroll
    for (int l = 0; l < LL; ++l)
        out[(size_t)row * LL + l] = w1n * a[i1 * LL + l] + w2n * a[i2 * LL + l];

    #pragma unroll
    for (int e = 0; e < EE; ++e)
        #pragma unroll
        for (int l = 0; l < LL; ++l)
            out[(size_t)NB * (LL + EE) + (size_t)row * (EE * LL) + e * LL + l] =
                (e == i1 || e == i2) ? a[e * LL + l] : 0.f;
}

extern "C" void kernel_launch(void* const* d_in, const int* in_sizes, int n_in,
                              void* d_out, int out_size, void* d_ws, size_t ws_size,
                              hipStream_t stream)
{
    const float* hs = (const float*)d_in[0];
    const float* W1 = (const float*)d_in[1];
    const float* b1 = (const float*)d_in[2];
    const float* W2 = (const float*)d_in[3];
    const float* b2 = (const float*)d_in[4];
    const float* We = (const float*)d_in[5];
    const float* be = (const float*)d_in[6];
    float* out = (float*)d_out;

    char* ws = (char*)d_ws;
    f16*   bHi = (f16*)(ws);                 // 1179648 B
    f16*   bLo = (f16*)(ws + 1179648);       // 1179648 B
    float* wsP = (float*)(ws + 2359296);     // 2621440 B
    float* wsA = (float*)(ws + 4980736);     // 327680 B  -> total 5308416 B

    hipLaunchKernelGGL(k0b_convB, dim3(144), dim3(256), 0, stream, W1, bHi, bLo);
    hipLaunchKernelGGL(k0_einsum, dim3(NB / 4), dim3(256), 0, stream, hs, We, be, wsA);
    hipLaunchKernelGGL(k1_gemm, dim3(512), dim3(256), 0, stream, hs, bHi, bLo, b1, W2, wsP);
    hipLaunchKernelGGL(k2_epilogue, dim3(NB / 256), dim3(256), 0, stream, wsP, wsA, b2, out);
}

// Round 9
// 86.717 us; speedup vs baseline: 4.7390x; 1.0352x over previous
//
#include <hip/hip_runtime.h>
#include <hip/hip_bf16.h>

#define NB 8192
#define SS 64
#define HH 768
#define EE 5
#define LL 2

typedef _Float16 f16;
typedef f16 f16x8 __attribute__((ext_vector_type(8)));
typedef float f32x4 __attribute__((ext_vector_type(4)));

#define LO_SCALE 2048.0f
#define LO_INV   4.8828125e-4f   // 1/2048

// ---------------- K0 (fused): blocks [0,144): W1 -> transposed f16 hi/lo(x2048)
//                              blocks [144,2192): all_logits einsum ----------------
__global__ __launch_bounds__(256)
void k0_fused(const float* __restrict__ W1, const float* __restrict__ hs,
              const float* __restrict__ We, const float* __restrict__ be,
              f16* __restrict__ bHi, f16* __restrict__ bLo, float* __restrict__ wsA)
{
    __shared__ float tile[64][65];
    const int tid = threadIdx.x;

    if (blockIdx.x < 144) {
        // ---- convB part (verbatim R5 k0b) ----
        const int kb = (blockIdx.x % 12) * 64, nb = (blockIdx.x / 12) * 64;
        const int cc = tid & 63, rr = tid >> 6;
        #pragma unroll
        for (int i = 0; i < 16; ++i) {
            int r = i * 4 + rr;
            tile[r][cc] = W1[(size_t)(kb + r) * HH + nb + cc];
        }
        __syncthreads();
        const int n = tid >> 2, kc = (tid & 3) * 16;
        f16 hh[16], ll[16];
        #pragma unroll
        for (int j = 0; j < 16; ++j) {
            float x = tile[kc + j][n];
            f16 h = (f16)x;
            hh[j] = h;
            ll[j] = (f16)((x - (float)h) * LO_SCALE);
        }
        f16* dh = bHi + (size_t)(nb + n) * HH + kb + kc;
        f16* dl = bLo + (size_t)(nb + n) * HH + kb + kc;
        f16x8 t;
        t = (f16x8){hh[0],hh[1],hh[2],hh[3],hh[4],hh[5],hh[6],hh[7]};       *(f16x8*)(dh)     = t;
        t = (f16x8){hh[8],hh[9],hh[10],hh[11],hh[12],hh[13],hh[14],hh[15]}; *(f16x8*)(dh + 8) = t;
        t = (f16x8){ll[0],ll[1],ll[2],ll[3],ll[4],ll[5],ll[6],ll[7]};       *(f16x8*)(dl)     = t;
        t = (f16x8){ll[8],ll[9],ll[10],ll[11],ll[12],ll[13],ll[14],ll[15]}; *(f16x8*)(dl + 8) = t;
        return;
    }

    // ---- einsum part (verbatim R5 k0, row base shifted) ----
    const int wid = tid >> 6, lane = tid & 63;
    const size_t row = (size_t)(blockIdx.x - 144) * 4 + wid;
    const float* rp = hs + row * (SS * HH);
    const int kb = lane * 12;

    float4 va = *(const float4*)(rp + kb);
    float4 vb = *(const float4*)(rp + kb + 4);
    float4 vc = *(const float4*)(rp + kb + 8);
    float v[12] = {va.x, va.y, va.z, va.w, vb.x, vb.y, vb.z, vb.w, vc.x, vc.y, vc.z, vc.w};

    float acc[EE * LL];
    #pragma unroll
    for (int u = 0; u < EE * LL; ++u) acc[u] = 0.f;
    #pragma unroll
    for (int j = 0; j < 12; ++j) {
        float c = v[j];
        int h = kb + j;
        #pragma unroll
        for (int e = 0; e < EE; ++e) {
            float2 w = *(const float2*)(We + (size_t)e * (HH * LL) + h * 2);
            acc[2 * e]     += c * w.x;
            acc[2 * e + 1] += c * w.y;
        }
    }
    #pragma unroll
    for (int u = 0; u < EE * LL; ++u) {
        float s = acc[u];
        s += __shfl_xor(s, 1);  s += __shfl_xor(s, 2);  s += __shfl_xor(s, 4);
        s += __shfl_xor(s, 8);  s += __shfl_xor(s, 16); s += __shfl_xor(s, 32);
        if (lane == 0) wsA[(size_t)u * NB + row] = s + be[u];
    }
}

// ---------------- K1: MFMA GEMM, in-register f16 hi/lo split of A ----------------
// BYTE-EXACT copy of the R5-PASSED kernel, except __launch_bounds__ 2 -> 3.
// LDS 28 KB: aHi [0,8K) | aLo [8K,16K) | bHi [16K,22528) | bLo [22528,28672)
// row r at byte r*64 in its region; phys kseg slot s holds logical kseg s^((r>>1)&3)

__global__ __launch_bounds__(256, 3)
void k1_gemm(const float* __restrict__ hs, const f16* __restrict__ bHi,
             const f16* __restrict__ bLo, const float* __restrict__ b1,
             const float* __restrict__ W2, float* __restrict__ wsP)
{
    __shared__ alignas(16) char lds[28672];
    const int tid = threadIdx.x, wid = tid >> 6, lane = tid & 63;
    const int mb = blockIdx.x & 63, nb = blockIdx.x >> 6;   // bid%8 = mb%8 -> XCD grouping
    const int r0 = mb * 128, n0 = nb * 96;
    const int wm = wid >> 1, wn = wid & 1;

    f32x4 accH[4][3], accL[4][3];
    #pragma unroll
    for (int i = 0; i < 4; ++i)
        #pragma unroll
        for (int j = 0; j < 3; ++j) {
            accH[i][j] = (f32x4){0.f, 0.f, 0.f, 0.f};
            accL[i][j] = (f32x4){0.f, 0.f, 0.f, 0.f};
        }

    // ---- A staging: thread -> (row ar, k-half ah of 16 floats) ----
    const int ar = tid >> 1;
    const int ah = tid & 1;
    const float* ap = hs + (size_t)(r0 + ar) * (SS * HH) + ah * 16;
    const int as_ = (ar >> 1) & 3;
    const int aoff0 = ar * 64 + (((2 * ah + 0) ^ as_) & 3) * 16;
    const int aoff1 = ar * 64 + (((2 * ah + 1) ^ as_) & 3) * 16;

    // ---- B staging: 12 chunks of 1 KB; 3 per thread-quarter ----
    const f16* gptrB[3];
    int boff[3];
    #pragma unroll
    for (int j = 0; j < 3; ++j) {
        int q = j * 4 + wid;                         // 0..11
        const f16* base = (q < 6) ? bHi : bLo;
        int sr0 = ((q < 6) ? q : q - 6) * 16;
        int srow = sr0 + (lane >> 2);
        int ks = ((lane & 3) ^ (srow >> 1)) & 3;
        gptrB[j] = base + (size_t)(n0 + srow) * HH + ks * 8;
        boff[j]  = 16384 + q * 1024 + (lane >> 2) * 64 + (lane & 3) * 16;
    }

    float4 pa[4];
    f16x8 pb[3];
    #pragma unroll
    for (int j = 0; j < 4; ++j) pa[j] = *(const float4*)(ap + 4 * j);
    #pragma unroll
    for (int j = 0; j < 3; ++j) pb[j] = *(const f16x8*)(gptrB[j]);

    const int arow_base = wm * 64 + (lane & 15);
    const int bcol_base = wn * 48 + (lane & 15);
    const int lg = lane >> 4;

    for (int t = 0; t < 24; ++t) {
        __syncthreads();                      // previous compute done reading LDS
        // convert A to f16 hi / lo*2048 and write fragments
        {
            float u[16] = {pa[0].x, pa[0].y, pa[0].z, pa[0].w,
                           pa[1].x, pa[1].y, pa[1].z, pa[1].w,
                           pa[2].x, pa[2].y, pa[2].z, pa[2].w,
                           pa[3].x, pa[3].y, pa[3].z, pa[3].w};
            f16 hi[16], lo[16];
            #pragma unroll
            for (int i = 0; i < 16; ++i) {
                f16 h = (f16)u[i];
                hi[i] = h;
                lo[i] = (f16)((u[i] - (float)h) * LO_SCALE);
            }
            *(f16x8*)(lds + aoff0) = (f16x8){hi[0],hi[1],hi[2],hi[3],hi[4],hi[5],hi[6],hi[7]};
            *(f16x8*)(lds + aoff1) = (f16x8){hi[8],hi[9],hi[10],hi[11],hi[12],hi[13],hi[14],hi[15]};
            *(f16x8*)(lds + 8192 + aoff0) = (f16x8){lo[0],lo[1],lo[2],lo[3],lo[4],lo[5],lo[6],lo[7]};
            *(f16x8*)(lds + 8192 + aoff1) = (f16x8){lo[8],lo[9],lo[10],lo[11],lo[12],lo[13],lo[14],lo[15]};
        }
        #pragma unroll
        for (int j = 0; j < 3; ++j) *(f16x8*)(lds + boff[j]) = pb[j];
        __syncthreads();                      // staging visible

        if (t < 23) {                         // prefetch next tile (hides under MFMA)
            #pragma unroll
            for (int j = 0; j < 4; ++j) pa[j] = *(const float4*)(ap + (t + 1) * 32 + 4 * j);
            #pragma unroll
            for (int j = 0; j < 3; ++j) { gptrB[j] += 32; pb[j] = *(const f16x8*)(gptrB[j]); }
        }

        f16x8 af[4][2], bf[3][2];
        #pragma unroll
        for (int mf = 0; mf < 4; ++mf) {
            int srow = arow_base + mf * 16;
            int off = srow * 64 + (((lg ^ (srow >> 1)) & 3) << 4);
            af[mf][0] = *(const f16x8*)(lds + off);
            af[mf][1] = *(const f16x8*)(lds + 8192 + off);
        }
        #pragma unroll
        for (int nf = 0; nf < 3; ++nf) {
            int scol = bcol_base + nf * 16;
            int off = scol * 64 + (((lg ^ (scol >> 1)) & 3) << 4);
            bf[nf][0] = *(const f16x8*)(lds + 16384 + off);
            bf[nf][1] = *(const f16x8*)(lds + 22528 + off);
        }
        #pragma unroll
        for (int mf = 0; mf < 4; ++mf)
            #pragma unroll
            for (int nf = 0; nf < 3; ++nf) {
                accH[mf][nf] = __builtin_amdgcn_mfma_f32_16x16x32_f16(af[mf][0], bf[nf][0], accH[mf][nf], 0, 0, 0);
                accL[mf][nf] = __builtin_amdgcn_mfma_f32_16x16x32_f16(af[mf][0], bf[nf][1], accL[mf][nf], 0, 0, 0);
                accL[mf][nf] = __builtin_amdgcn_mfma_f32_16x16x32_f16(af[mf][1], bf[nf][0], accL[mf][nf], 0, 0, 0);
            }
    }

    // ---- epilogue: combine scales, bias + relu + @W2 partials ----
    float lacc[4][4][EE];
    #pragma unroll
    for (int mf = 0; mf < 4; ++mf)
        #pragma unroll
        for (int r = 0; r < 4; ++r)
            #pragma unroll
            for (int e = 0; e < EE; ++e) lacc[mf][r][e] = 0.f;

    #pragma unroll
    for (int nf = 0; nf < 3; ++nf) {
        int gc = n0 + wn * 48 + nf * 16 + (lane & 15);
        float bb = b1[gc];
        float w[EE];
        #pragma unroll
        for (int e = 0; e < EE; ++e) w[e] = W2[gc * EE + e];
        #pragma unroll
        for (int mf = 0; mf < 4; ++mf)
            #pragma unroll
            for (int r = 0; r < 4; ++r) {
                float g = accH[mf][nf][r] + LO_INV * accL[mf][nf][r] + bb;
                g = fmaxf(g, 0.f);
                #pragma unroll
                for (int e = 0; e < EE; ++e) lacc[mf][r][e] += g * w[e];
            }
    }
    #pragma unroll
    for (int mf = 0; mf < 4; ++mf)
        #pragma unroll
        for (int r = 0; r < 4; ++r)
            #pragma unroll
            for (int e = 0; e < EE; ++e) {
                float s = lacc[mf][r][e];
                s += __shfl_xor(s, 1); s += __shfl_xor(s, 2);
                s += __shfl_xor(s, 4); s += __shfl_xor(s, 8);
                lacc[mf][r][e] = s;
            }
    if ((lane & 15) == 0) {
        int rg = lane >> 4;
        int p = nb * 2 + wn;
        #pragma unroll
        for (int mf = 0; mf < 4; ++mf)
            #pragma unroll
            for (int r = 0; r < 4; ++r)
                #pragma unroll
                for (int e = 0; e < EE; ++e)
                    wsP[(size_t)(p * EE + e) * NB + r0 + wm * 64 + mf * 16 + rg * 4 + r] = lacc[mf][r][e];
    }
}

// ---------------- K2: softmax, top-2, outputs (verbatim R5) ----------------
__global__ __launch_bounds__(256)
void k2_epilogue(const float* __restrict__ wsP, const float* __restrict__ wsA,
                 const float* __restrict__ b2, float* __restrict__ out)
{
    int row = blockIdx.x * 256 + threadIdx.x;
    if (row >= NB) return;

    float lg[EE];
    #pragma unroll
    for (int e = 0; e < EE; ++e) {
        float s = b2[e];
        #pragma unroll
        for (int p = 0; p < 16; ++p)
            s += wsP[(size_t)(p * EE + e) * NB + row];
        lg[e] = s;
    }

    float m = lg[0];
    #pragma unroll
    for (int e = 1; e < EE; ++e) m = fmaxf(m, lg[e]);
    float pr[EE]; float sum = 0.f;
    #pragma unroll
    for (int e = 0; e < EE; ++e) { pr[e] = expf(lg[e] - m); sum += pr[e]; }
    float inv = 1.f / sum;
    #pragma unroll
    for (int e = 0; e < EE; ++e) pr[e] *= inv;

    #pragma unroll
    for (int e = 0; e < EE; ++e)
        out[(size_t)NB * LL + (size_t)row * EE + e] = pr[e];

    int i1 = 0; float v1 = pr[0];
    #pragma unroll
    for (int e = 1; e < EE; ++e) if (pr[e] > v1) { v1 = pr[e]; i1 = e; }
    int i2 = -1; float v2 = -1.f;
    #pragma unroll
    for (int e = 0; e < EE; ++e) if (e != i1 && pr[e] > v2) { v2 = pr[e]; i2 = e; }

    float wsum = v1 + v2;
    float w1n = v1 / wsum, w2n = v2 / wsum;

    float a[EE * LL];
    #pragma unroll
    for (int el = 0; el < EE * LL; ++el) a[el] = wsA[(size_t)el * NB + row];

    #pragma unroll
    for (int l = 0; l < LL; ++l)
        out[(size_t)row * LL + l] = w1n * a[i1 * LL + l] + w2n * a[i2 * LL + l];

    #pragma unroll
    for (int e = 0; e < EE; ++e)
        #pragma unroll
        for (int l = 0; l < LL; ++l)
            out[(size_t)NB * (LL + EE) + (size_t)row * (EE * LL) + e * LL + l] =
                (e == i1 || e == i2) ? a[e * LL + l] : 0.f;
}

extern "C" void kernel_launch(void* const* d_in, const int* in_sizes, int n_in,
                              void* d_out, int out_size, void* d_ws, size_t ws_size,
                              hipStream_t stream)
{
    const float* hs = (const float*)d_in[0];
    const float* W1 = (const float*)d_in[1];
    const float* b1 = (const float*)d_in[2];
    const float* W2 = (const float*)d_in[3];
    const float* b2 = (const float*)d_in[4];
    const float* We = (const float*)d_in[5];
    const float* be = (const float*)d_in[6];
    float* out = (float*)d_out;

    char* ws = (char*)d_ws;
    f16*   bHi = (f16*)(ws);                 // 1179648 B
    f16*   bLo = (f16*)(ws + 1179648);       // 1179648 B
    float* wsP = (float*)(ws + 2359296);     // 2621440 B
    float* wsA = (float*)(ws + 4980736);     // 327680 B  -> total 5308416 B

    hipLaunchKernelGGL(k0_fused, dim3(144 + NB / 4), dim3(256), 0, stream,
                       W1, hs, We, be, bHi, bLo, wsA);
    hipLaunchKernelGGL(k1_gemm, dim3(512), dim3(256), 0, stream, hs, bHi, bLo, b1, W2, wsP);
    hipLaunchKernelGGL(k2_epilogue, dim3(NB / 256), dim3(256), 0, stream, wsP, wsA, b2, out);
}

// Round 14
// 85.853 us; speedup vs baseline: 4.7867x; 1.0101x over previous
//
#include <hip/hip_runtime.h>
#include <hip/hip_bf16.h>

#define NB 8192
#define SS 64
#define HH 768
#define EE 5
#define LL 2

typedef _Float16 f16;
typedef f16 f16x8 __attribute__((ext_vector_type(8)));
typedef float f32x4 __attribute__((ext_vector_type(4)));

#define LO_SCALE 2048.0f
#define LO_INV   4.8828125e-4f   // 1/2048

// ---------------- K0 (fused): blocks [0,144): W1 -> transposed f16 hi/lo(x2048)
//                              blocks [144,2192): all_logits einsum ----------------
__global__ __launch_bounds__(256)
void k0_fused(const float* __restrict__ W1, const float* __restrict__ hs,
              const float* __restrict__ We, const float* __restrict__ be,
              f16* __restrict__ bHi, f16* __restrict__ bLo, float* __restrict__ wsA)
{
    __shared__ float tile[64][65];
    const int tid = threadIdx.x;

    if (blockIdx.x < 144) {
        // ---- convB part (verbatim R5 k0b) ----
        const int kb = (blockIdx.x % 12) * 64, nb = (blockIdx.x / 12) * 64;
        const int cc = tid & 63, rr = tid >> 6;
        #pragma unroll
        for (int i = 0; i < 16; ++i) {
            int r = i * 4 + rr;
            tile[r][cc] = W1[(size_t)(kb + r) * HH + nb + cc];
        }
        __syncthreads();
        const int n = tid >> 2, kc = (tid & 3) * 16;
        f16 hh[16], ll[16];
        #pragma unroll
        for (int j = 0; j < 16; ++j) {
            float x = tile[kc + j][n];
            f16 h = (f16)x;
            hh[j] = h;
            ll[j] = (f16)((x - (float)h) * LO_SCALE);
        }
        f16* dh = bHi + (size_t)(nb + n) * HH + kb + kc;
        f16* dl = bLo + (size_t)(nb + n) * HH + kb + kc;
        f16x8 t;
        t = (f16x8){hh[0],hh[1],hh[2],hh[3],hh[4],hh[5],hh[6],hh[7]};       *(f16x8*)(dh)     = t;
        t = (f16x8){hh[8],hh[9],hh[10],hh[11],hh[12],hh[13],hh[14],hh[15]}; *(f16x8*)(dh + 8) = t;
        t = (f16x8){ll[0],ll[1],ll[2],ll[3],ll[4],ll[5],ll[6],ll[7]};       *(f16x8*)(dl)     = t;
        t = (f16x8){ll[8],ll[9],ll[10],ll[11],ll[12],ll[13],ll[14],ll[15]}; *(f16x8*)(dl + 8) = t;
        return;
    }

    // ---- einsum part (verbatim R5 k0, row base shifted) ----
    const int wid = tid >> 6, lane = tid & 63;
    const size_t row = (size_t)(blockIdx.x - 144) * 4 + wid;
    const float* rp = hs + row * (SS * HH);
    const int kb = lane * 12;

    float4 va = *(const float4*)(rp + kb);
    float4 vb = *(const float4*)(rp + kb + 4);
    float4 vc = *(const float4*)(rp + kb + 8);
    float v[12] = {va.x, va.y, va.z, va.w, vb.x, vb.y, vb.z, vb.w, vc.x, vc.y, vc.z, vc.w};

    float acc[EE * LL];
    #pragma unroll
    for (int u = 0; u < EE * LL; ++u) acc[u] = 0.f;
    #pragma unroll
    for (int j = 0; j < 12; ++j) {
        float c = v[j];
        int h = kb + j;
        #pragma unroll
        for (int e = 0; e < EE; ++e) {
            float2 w = *(const float2*)(We + (size_t)e * (HH * LL) + h * 2);
            acc[2 * e]     += c * w.x;
            acc[2 * e + 1] += c * w.y;
        }
    }
    #pragma unroll
    for (int u = 0; u < EE * LL; ++u) {
        float s = acc[u];
        s += __shfl_xor(s, 1);  s += __shfl_xor(s, 2);  s += __shfl_xor(s, 4);
        s += __shfl_xor(s, 8);  s += __shfl_xor(s, 16); s += __shfl_xor(s, 32);
        if (lane == 0) wsA[(size_t)u * NB + row] = s + be[u];
    }
}

// ---------------- K1: MFMA GEMM, in-register f16 hi/lo split of A ----------------
// BYTE-EXACT copy of the R5-PASSED kernel, except __launch_bounds__ 2 -> 3.
// LDS 28 KB: aHi [0,8K) | aLo [8K,16K) | bHi [16K,22528) | bLo [22528,28672)
// row r at byte r*64 in its region; phys kseg slot s holds logical kseg s^((r>>1)&3)

__global__ __launch_bounds__(256, 3)
void k1_gemm(const float* __restrict__ hs, const f16* __restrict__ bHi,
             const f16* __restrict__ bLo, const float* __restrict__ b1,
             const float* __restrict__ W2, float* __restrict__ wsP)
{
    __shared__ alignas(16) char lds[28672];
    const int tid = threadIdx.x, wid = tid >> 6, lane = tid & 63;
    const int mb = blockIdx.x & 63, nb = blockIdx.x >> 6;   // bid%8 = mb%8 -> XCD grouping
    const int r0 = mb * 128, n0 = nb * 96;
    const int wm = wid >> 1, wn = wid & 1;

    f32x4 accH[4][3], accL[4][3];
    #pragma unroll
    for (int i = 0; i < 4; ++i)
        #pragma unroll
        for (int j = 0; j < 3; ++j) {
            accH[i][j] = (f32x4){0.f, 0.f, 0.f, 0.f};
            accL[i][j] = (f32x4){0.f, 0.f, 0.f, 0.f};
        }

    // ---- A staging: thread -> (row ar, k-half ah of 16 floats) ----
    const int ar = tid >> 1;
    const int ah = tid & 1;
    const float* ap = hs + (size_t)(r0 + ar) * (SS * HH) + ah * 16;
    const int as_ = (ar >> 1) & 3;
    const int aoff0 = ar * 64 + (((2 * ah + 0) ^ as_) & 3) * 16;
    const int aoff1 = ar * 64 + (((2 * ah + 1) ^ as_) & 3) * 16;

    // ---- B staging: 12 chunks of 1 KB; 3 per thread-quarter ----
    const f16* gptrB[3];
    int boff[3];
    #pragma unroll
    for (int j = 0; j < 3; ++j) {
        int q = j * 4 + wid;                         // 0..11
        const f16* base = (q < 6) ? bHi : bLo;
        int sr0 = ((q < 6) ? q : q - 6) * 16;
        int srow = sr0 + (lane >> 2);
        int ks = ((lane & 3) ^ (srow >> 1)) & 3;
        gptrB[j] = base + (size_t)(n0 + srow) * HH + ks * 8;
        boff[j]  = 16384 + q * 1024 + (lane >> 2) * 64 + (lane & 3) * 16;
    }

    float4 pa[4];
    f16x8 pb[3];
    #pragma unroll
    for (int j = 0; j < 4; ++j) pa[j] = *(const float4*)(ap + 4 * j);
    #pragma unroll
    for (int j = 0; j < 3; ++j) pb[j] = *(const f16x8*)(gptrB[j]);

    const int arow_base = wm * 64 + (lane & 15);
    const int bcol_base = wn * 48 + (lane & 15);
    const int lg = lane >> 4;

    for (int t = 0; t < 24; ++t) {
        __syncthreads();                      // previous compute done reading LDS
        // convert A to f16 hi / lo*2048 and write fragments
        {
            float u[16] = {pa[0].x, pa[0].y, pa[0].z, pa[0].w,
                           pa[1].x, pa[1].y, pa[1].z, pa[1].w,
                           pa[2].x, pa[2].y, pa[2].z, pa[2].w,
                           pa[3].x, pa[3].y, pa[3].z, pa[3].w};
            f16 hi[16], lo[16];
            #pragma unroll
            for (int i = 0; i < 16; ++i) {
                f16 h = (f16)u[i];
                hi[i] = h;
                lo[i] = (f16)((u[i] - (float)h) * LO_SCALE);
            }
            *(f16x8*)(lds + aoff0) = (f16x8){hi[0],hi[1],hi[2],hi[3],hi[4],hi[5],hi[6],hi[7]};
            *(f16x8*)(lds + aoff1) = (f16x8){hi[8],hi[9],hi[10],hi[11],hi[12],hi[13],hi[14],hi[15]};
            *(f16x8*)(lds + 8192 + aoff0) = (f16x8){lo[0],lo[1],lo[2],lo[3],lo[4],lo[5],lo[6],lo[7]};
            *(f16x8*)(lds + 8192 + aoff1) = (f16x8){lo[8],lo[9],lo[10],lo[11],lo[12],lo[13],lo[14],lo[15]};
        }
        #pragma unroll
        for (int j = 0; j < 3; ++j) *(f16x8*)(lds + boff[j]) = pb[j];
        __syncthreads();                      // staging visible

        if (t < 23) {                         // prefetch next tile (hides under MFMA)
            #pragma unroll
            for (int j = 0; j < 4; ++j) pa[j] = *(const float4*)(ap + (t + 1) * 32 + 4 * j);
            #pragma unroll
            for (int j = 0; j < 3; ++j) { gptrB[j] += 32; pb[j] = *(const f16x8*)(gptrB[j]); }
        }

        f16x8 af[4][2], bf[3][2];
        #pragma unroll
        for (int mf = 0; mf < 4; ++mf) {
            int srow = arow_base + mf * 16;
            int off = srow * 64 + (((lg ^ (srow >> 1)) & 3) << 4);
            af[mf][0] = *(const f16x8*)(lds + off);
            af[mf][1] = *(const f16x8*)(lds + 8192 + off);
        }
        #pragma unroll
        for (int nf = 0; nf < 3; ++nf) {
            int scol = bcol_base + nf * 16;
            int off = scol * 64 + (((lg ^ (scol >> 1)) & 3) << 4);
            bf[nf][0] = *(const f16x8*)(lds + 16384 + off);
            bf[nf][1] = *(const f16x8*)(lds + 22528 + off);
        }
        #pragma unroll
        for (int mf = 0; mf < 4; ++mf)
            #pragma unroll
            for (int nf = 0; nf < 3; ++nf) {
                accH[mf][nf] = __builtin_amdgcn_mfma_f32_16x16x32_f16(af[mf][0], bf[nf][0], accH[mf][nf], 0, 0, 0);
                accL[mf][nf] = __builtin_amdgcn_mfma_f32_16x16x32_f16(af[mf][0], bf[nf][1], accL[mf][nf], 0, 0, 0);
                accL[mf][nf] = __builtin_amdgcn_mfma_f32_16x16x32_f16(af[mf][1], bf[nf][0], accL[mf][nf], 0, 0, 0);
            }
    }

    // ---- epilogue: combine scales, bias + relu + @W2 partials ----
    float lacc[4][4][EE];
    #pragma unroll
    for (int mf = 0; mf < 4; ++mf)
        #pragma unroll
        for (int r = 0; r < 4; ++r)
            #pragma unroll
            for (int e = 0; e < EE; ++e) lacc[mf][r][e] = 0.f;

    #pragma unroll
    for (int nf = 0; nf < 3; ++nf) {
        int gc = n0 + wn * 48 + nf * 16 + (lane & 15);
        float bb = b1[gc];
        float w[EE];
        #pragma unroll
        for (int e = 0; e < EE; ++e) w[e] = W2[gc * EE + e];
        #pragma unroll
        for (int mf = 0; mf < 4; ++mf)
            #pragma unroll
            for (int r = 0; r < 4; ++r) {
                float g = accH[mf][nf][r] + LO_INV * accL[mf][nf][r] + bb;
                g = fmaxf(g, 0.f);
                #pragma unroll
                for (int e = 0; e < EE; ++e) lacc[mf][r][e] += g * w[e];
            }
    }
    #pragma unroll
    for (int mf = 0; mf < 4; ++mf)
        #pragma unroll
        for (int r = 0; r < 4; ++r)
            #pragma unroll
            for (int e = 0; e < EE; ++e) {
                float s = lacc[mf][r][e];
                s += __shfl_xor(s, 1); s += __shfl_xor(s, 2);
                s += __shfl_xor(s, 4); s += __shfl_xor(s, 8);
                lacc[mf][r][e] = s;
            }
    if ((lane & 15) == 0) {
        int rg = lane >> 4;
        int p = nb * 2 + wn;
        #pragma unroll
        for (int mf = 0; mf < 4; ++mf)
            #pragma unroll
            for (int r = 0; r < 4; ++r)
                #pragma unroll
                for (int e = 0; e < EE; ++e)
                    wsP[(size_t)(p * EE + e) * NB + r0 + wm * 64 + mf * 16 + rg * 4 + r] = lacc[mf][r][e];
    }
}

// ---------------- K2: softmax, top-2, outputs (verbatim R5) ----------------
__global__ __launch_bounds__(256)
void k2_epilogue(const float* __restrict__ wsP, const float* __restrict__ wsA,
                 const float* __restrict__ b2, float* __restrict__ out)
{
    int row = blockIdx.x * 256 + threadIdx.x;
    if (row >= NB) return;

    float lg[EE];
    #pragma unroll
    for (int e = 0; e < EE; ++e) {
        float s = b2[e];
        #pragma unroll
        for (int p = 0; p < 16; ++p)
            s += wsP[(size_t)(p * EE + e) * NB + row];
        lg[e] = s;
    }

    float m = lg[0];
    #pragma unroll
    for (int e = 1; e < EE; ++e) m = fmaxf(m, lg[e]);
    float pr[EE]; float sum = 0.f;
    #pragma unroll
    for (int e = 0; e < EE; ++e) { pr[e] = expf(lg[e] - m); sum += pr[e]; }
    float inv = 1.f / sum;
    #pragma unroll
    for (int e = 0; e < EE; ++e) pr[e] *= inv;

    #pragma unroll
    for (int e = 0; e < EE; ++e)
        out[(size_t)NB * LL + (size_t)row * EE + e] = pr[e];

    int i1 = 0; float v1 = pr[0];
    #pragma unroll
    for (int e = 1; e < EE; ++e) if (pr[e] > v1) { v1 = pr[e]; i1 = e; }
    int i2 = -1; float v2 = -1.f;
    #pragma unroll
    for (int e = 0; e < EE; ++e) if (e != i1 && pr[e] > v2) { v2 = pr[e]; i2 = e; }

    float wsum = v1 + v2;
    float w1n = v1 / wsum, w2n = v2 / wsum;

    float a[EE * LL];
    #pragma unroll
    for (int el = 0; el < EE * LL; ++el) a[el] = wsA[(size_t)el * NB + row];

    #pragma unroll
    for (int l = 0; l < LL; ++l)
        out[(size_t)row * LL + l] = w1n * a[i1 * LL + l] + w2n * a[i2 * LL + l];

    #pragma unroll
    for (int e = 0; e < EE; ++e)
        #pragma unroll
        for (int l = 0; l < LL; ++l)
            out[(size_t)NB * (LL + EE) + (size_t)row * (EE * LL) + e * LL + l] =
                (e == i1 || e == i2) ? a[e * LL + l] : 0.f;
}

extern "C" void kernel_launch(void* const* d_in, const int* in_sizes, int n_in,
                              void* d_out, int out_size, void* d_ws, size_t ws_size,
                              hipStream_t stream)
{
    const float* hs = (const float*)d_in[0];
    const float* W1 = (const float*)d_in[1];
    const float* b1 = (const float*)d_in[2];
    const float* W2 = (const float*)d_in[3];
    const float* b2 = (const float*)d_in[4];
    const float* We = (const float*)d_in[5];
    const float* be = (const float*)d_in[6];
    float* out = (float*)d_out;

    char* ws = (char*)d_ws;
    f16*   bHi = (f16*)(ws);                 // 1179648 B
    f16*   bLo = (f16*)(ws + 1179648);       // 1179648 B
    float* wsP = (float*)(ws + 2359296);     // 2621440 B
    float* wsA = (float*)(ws + 4980736);     // 327680 B  -> total 5308416 B

    hipLaunchKernelGGL(k0_fused, dim3(144 + NB / 4), dim3(256), 0, stream,
                       W1, hs, We, be, bHi, bLo, wsA);
    hipLaunchKernelGGL(k1_gemm, dim3(512), dim3(256), 0, stream, hs, bHi, bLo, b1, W2, wsP);
    hipLaunchKernelGGL(k2_epilogue, dim3(NB / 256), dim3(256), 0, stream, wsP, wsA, b2, out);
}

// Round 15
// 85.716 us; speedup vs baseline: 4.7943x; 1.0016x over previous
//
#include <hip/hip_runtime.h>
#include <hip/hip_bf16.h>

#define NB 8192
#define SS 64
#define HH 768
#define EE 5
#define LL 2

typedef _Float16 f16;
typedef f16 f16x8 __attribute__((ext_vector_type(8)));
typedef float f32x4 __attribute__((ext_vector_type(4)));

#define LO_SCALE 2048.0f
#define LO_INV   4.8828125e-4f   // 1/2048

// ---------------- K0 (fused): blocks [0,144): W1 -> transposed f16 hi/lo(x2048)
//                              blocks [144,2192): all_logits einsum ----------------
__global__ __launch_bounds__(256)
void k0_fused(const float* __restrict__ W1, const float* __restrict__ hs,
              const float* __restrict__ We, const float* __restrict__ be,
              f16* __restrict__ bHi, f16* __restrict__ bLo, float* __restrict__ wsA)
{
    __shared__ float tile[64][65];
    const int tid = threadIdx.x;

    if (blockIdx.x < 144) {
        // ---- convB part (verbatim R5 k0b) ----
        const int kb = (blockIdx.x % 12) * 64, nb = (blockIdx.x / 12) * 64;
        const int cc = tid & 63, rr = tid >> 6;
        #pragma unroll
        for (int i = 0; i < 16; ++i) {
            int r = i * 4 + rr;
            tile[r][cc] = W1[(size_t)(kb + r) * HH + nb + cc];
        }
        __syncthreads();
        const int n = tid >> 2, kc = (tid & 3) * 16;
        f16 hh[16], ll[16];
        #pragma unroll
        for (int j = 0; j < 16; ++j) {
            float x = tile[kc + j][n];
            f16 h = (f16)x;
            hh[j] = h;
            ll[j] = (f16)((x - (float)h) * LO_SCALE);
        }
        f16* dh = bHi + (size_t)(nb + n) * HH + kb + kc;
        f16* dl = bLo + (size_t)(nb + n) * HH + kb + kc;
        f16x8 t;
        t = (f16x8){hh[0],hh[1],hh[2],hh[3],hh[4],hh[5],hh[6],hh[7]};       *(f16x8*)(dh)     = t;
        t = (f16x8){hh[8],hh[9],hh[10],hh[11],hh[12],hh[13],hh[14],hh[15]}; *(f16x8*)(dh + 8) = t;
        t = (f16x8){ll[0],ll[1],ll[2],ll[3],ll[4],ll[5],ll[6],ll[7]};       *(f16x8*)(dl)     = t;
        t = (f16x8){ll[8],ll[9],ll[10],ll[11],ll[12],ll[13],ll[14],ll[15]}; *(f16x8*)(dl + 8) = t;
        return;
    }

    // ---- einsum part (verbatim R5 k0, row base shifted) ----
    const int wid = tid >> 6, lane = tid & 63;
    const size_t row = (size_t)(blockIdx.x - 144) * 4 + wid;
    const float* rp = hs + row * (SS * HH);
    const int kb = lane * 12;

    float4 va = *(const float4*)(rp + kb);
    float4 vb = *(const float4*)(rp + kb + 4);
    float4 vc = *(const float4*)(rp + kb + 8);
    float v[12] = {va.x, va.y, va.z, va.w, vb.x, vb.y, vb.z, vb.w, vc.x, vc.y, vc.z, vc.w};

    float acc[EE * LL];
    #pragma unroll
    for (int u = 0; u < EE * LL; ++u) acc[u] = 0.f;
    #pragma unroll
    for (int j = 0; j < 12; ++j) {
        float c = v[j];
        int h = kb + j;
        #pragma unroll
        for (int e = 0; e < EE; ++e) {
            float2 w = *(const float2*)(We + (size_t)e * (HH * LL) + h * 2);
            acc[2 * e]     += c * w.x;
            acc[2 * e + 1] += c * w.y;
        }
    }
    #pragma unroll
    for (int u = 0; u < EE * LL; ++u) {
        float s = acc[u];
        s += __shfl_xor(s, 1);  s += __shfl_xor(s, 2);  s += __shfl_xor(s, 4);
        s += __shfl_xor(s, 8);  s += __shfl_xor(s, 16); s += __shfl_xor(s, 32);
        if (lane == 0) wsA[(size_t)u * NB + row] = s + be[u];
    }
}

// ---------------- K1: MFMA GEMM, in-register f16 hi/lo split of A ----------------
// BYTE-EXACT copy of the R5-PASSED kernel, except __launch_bounds__ 2 -> 3.
// LDS 28 KB: aHi [0,8K) | aLo [8K,16K) | bHi [16K,22528) | bLo [22528,28672)
// row r at byte r*64 in its region; phys kseg slot s holds logical kseg s^((r>>1)&3)

__global__ __launch_bounds__(256, 3)
void k1_gemm(const float* __restrict__ hs, const f16* __restrict__ bHi,
             const f16* __restrict__ bLo, const float* __restrict__ b1,
             const float* __restrict__ W2, float* __restrict__ wsP)
{
    __shared__ alignas(16) char lds[28672];
    const int tid = threadIdx.x, wid = tid >> 6, lane = tid & 63;
    const int mb = blockIdx.x & 63, nb = blockIdx.x >> 6;   // bid%8 = mb%8 -> XCD grouping
    const int r0 = mb * 128, n0 = nb * 96;
    const int wm = wid >> 1, wn = wid & 1;

    f32x4 accH[4][3], accL[4][3];
    #pragma unroll
    for (int i = 0; i < 4; ++i)
        #pragma unroll
        for (int j = 0; j < 3; ++j) {
            accH[i][j] = (f32x4){0.f, 0.f, 0.f, 0.f};
            accL[i][j] = (f32x4){0.f, 0.f, 0.f, 0.f};
        }

    // ---- A staging: thread -> (row ar, k-half ah of 16 floats) ----
    const int ar = tid >> 1;
    const int ah = tid & 1;
    const float* ap = hs + (size_t)(r0 + ar) * (SS * HH) + ah * 16;
    const int as_ = (ar >> 1) & 3;
    const int aoff0 = ar * 64 + (((2 * ah + 0) ^ as_) & 3) * 16;
    const int aoff1 = ar * 64 + (((2 * ah + 1) ^ as_) & 3) * 16;

    // ---- B staging: 12 chunks of 1 KB; 3 per thread-quarter ----
    const f16* gptrB[3];
    int boff[3];
    #pragma unroll
    for (int j = 0; j < 3; ++j) {
        int q = j * 4 + wid;                         // 0..11
        const f16* base = (q < 6) ? bHi : bLo;
        int sr0 = ((q < 6) ? q : q - 6) * 16;
        int srow = sr0 + (lane >> 2);
        int ks = ((lane & 3) ^ (srow >> 1)) & 3;
        gptrB[j] = base + (size_t)(n0 + srow) * HH + ks * 8;
        boff[j]  = 16384 + q * 1024 + (lane >> 2) * 64 + (lane & 3) * 16;
    }

    float4 pa[4];
    f16x8 pb[3];
    #pragma unroll
    for (int j = 0; j < 4; ++j) pa[j] = *(const float4*)(ap + 4 * j);
    #pragma unroll
    for (int j = 0; j < 3; ++j) pb[j] = *(const f16x8*)(gptrB[j]);

    const int arow_base = wm * 64 + (lane & 15);
    const int bcol_base = wn * 48 + (lane & 15);
    const int lg = lane >> 4;

    for (int t = 0; t < 24; ++t) {
        __syncthreads();                      // previous compute done reading LDS
        // convert A to f16 hi / lo*2048 and write fragments
        {
            float u[16] = {pa[0].x, pa[0].y, pa[0].z, pa[0].w,
                           pa[1].x, pa[1].y, pa[1].z, pa[1].w,
                           pa[2].x, pa[2].y, pa[2].z, pa[2].w,
                           pa[3].x, pa[3].y, pa[3].z, pa[3].w};
            f16 hi[16], lo[16];
            #pragma unroll
            for (int i = 0; i < 16; ++i) {
                f16 h = (f16)u[i];
                hi[i] = h;
                lo[i] = (f16)((u[i] - (float)h) * LO_SCALE);
            }
            *(f16x8*)(lds + aoff0) = (f16x8){hi[0],hi[1],hi[2],hi[3],hi[4],hi[5],hi[6],hi[7]};
            *(f16x8*)(lds + aoff1) = (f16x8){hi[8],hi[9],hi[10],hi[11],hi[12],hi[13],hi[14],hi[15]};
            *(f16x8*)(lds + 8192 + aoff0) = (f16x8){lo[0],lo[1],lo[2],lo[3],lo[4],lo[5],lo[6],lo[7]};
            *(f16x8*)(lds + 8192 + aoff1) = (f16x8){lo[8],lo[9],lo[10],lo[11],lo[12],lo[13],lo[14],lo[15]};
        }
        #pragma unroll
        for (int j = 0; j < 3; ++j) *(f16x8*)(lds + boff[j]) = pb[j];
        __syncthreads();                      // staging visible

        if (t < 23) {                         // prefetch next tile (hides under MFMA)
            #pragma unroll
            for (int j = 0; j < 4; ++j) pa[j] = *(const float4*)(ap + (t + 1) * 32 + 4 * j);
            #pragma unroll
            for (int j = 0; j < 3; ++j) { gptrB[j] += 32; pb[j] = *(const f16x8*)(gptrB[j]); }
        }

        f16x8 af[4][2], bf[3][2];
        #pragma unroll
        for (int mf = 0; mf < 4; ++mf) {
            int srow = arow_base + mf * 16;
            int off = srow * 64 + (((lg ^ (srow >> 1)) & 3) << 4);
            af[mf][0] = *(const f16x8*)(lds + off);
            af[mf][1] = *(const f16x8*)(lds + 8192 + off);
        }
        #pragma unroll
        for (int nf = 0; nf < 3; ++nf) {
            int scol = bcol_base + nf * 16;
            int off = scol * 64 + (((lg ^ (scol >> 1)) & 3) << 4);
            bf[nf][0] = *(const f16x8*)(lds + 16384 + off);
            bf[nf][1] = *(const f16x8*)(lds + 22528 + off);
        }
        #pragma unroll
        for (int mf = 0; mf < 4; ++mf)
            #pragma unroll
            for (int nf = 0; nf < 3; ++nf) {
                accH[mf][nf] = __builtin_amdgcn_mfma_f32_16x16x32_f16(af[mf][0], bf[nf][0], accH[mf][nf], 0, 0, 0);
                accL[mf][nf] = __builtin_amdgcn_mfma_f32_16x16x32_f16(af[mf][0], bf[nf][1], accL[mf][nf], 0, 0, 0);
                accL[mf][nf] = __builtin_amdgcn_mfma_f32_16x16x32_f16(af[mf][1], bf[nf][0], accL[mf][nf], 0, 0, 0);
            }
    }

    // ---- epilogue: combine scales, bias + relu + @W2 partials ----
    float lacc[4][4][EE];
    #pragma unroll
    for (int mf = 0; mf < 4; ++mf)
        #pragma unroll
        for (int r = 0; r < 4; ++r)
            #pragma unroll
            for (int e = 0; e < EE; ++e) lacc[mf][r][e] = 0.f;

    #pragma unroll
    for (int nf = 0; nf < 3; ++nf) {
        int gc = n0 + wn * 48 + nf * 16 + (lane & 15);
        float bb = b1[gc];
        float w[EE];
        #pragma unroll
        for (int e = 0; e < EE; ++e) w[e] = W2[gc * EE + e];
        #pragma unroll
        for (int mf = 0; mf < 4; ++mf)
            #pragma unroll
            for (int r = 0; r < 4; ++r) {
                float g = accH[mf][nf][r] + LO_INV * accL[mf][nf][r] + bb;
                g = fmaxf(g, 0.f);
                #pragma unroll
                for (int e = 0; e < EE; ++e) lacc[mf][r][e] += g * w[e];
            }
    }
    #pragma unroll
    for (int mf = 0; mf < 4; ++mf)
        #pragma unroll
        for (int r = 0; r < 4; ++r)
            #pragma unroll
            for (int e = 0; e < EE; ++e) {
                float s = lacc[mf][r][e];
                s += __shfl_xor(s, 1); s += __shfl_xor(s, 2);
                s += __shfl_xor(s, 4); s += __shfl_xor(s, 8);
                lacc[mf][r][e] = s;
            }
    if ((lane & 15) == 0) {
        int rg = lane >> 4;
        int p = nb * 2 + wn;
        #pragma unroll
        for (int mf = 0; mf < 4; ++mf)
            #pragma unroll
            for (int r = 0; r < 4; ++r)
                #pragma unroll
                for (int e = 0; e < EE; ++e)
                    wsP[(size_t)(p * EE + e) * NB + r0 + wm * 64 + mf * 16 + rg * 4 + r] = lacc[mf][r][e];
    }
}

// ---------------- K2: softmax, top-2, outputs (verbatim R5) ----------------
__global__ __launch_bounds__(256)
void k2_epilogue(const float* __restrict__ wsP, const float* __restrict__ wsA,
                 const float* __restrict__ b2, float* __restrict__ out)
{
    int row = blockIdx.x * 256 + threadIdx.x;
    if (row >= NB) return;

    float lg[EE];
    #pragma unroll
    for (int e = 0; e < EE; ++e) {
        float s = b2[e];
        #pragma unroll
        for (int p = 0; p < 16; ++p)
            s += wsP[(size_t)(p * EE + e) * NB + row];
        lg[e] = s;
    }

    float m = lg[0];
    #pragma unroll
    for (int e = 1; e < EE; ++e) m = fmaxf(m, lg[e]);
    float pr[EE]; float sum = 0.f;
    #pragma unroll
    for (int e = 0; e < EE; ++e) { pr[e] = expf(lg[e] - m); sum += pr[e]; }
    float inv = 1.f / sum;
    #pragma unroll
    for (int e = 0; e < EE; ++e) pr[e] *= inv;

    #pragma unroll
    for (int e = 0; e < EE; ++e)
        out[(size_t)NB * LL + (size_t)row * EE + e] = pr[e];

    int i1 = 0; float v1 = pr[0];
    #pragma unroll
    for (int e = 1; e < EE; ++e) if (pr[e] > v1) { v1 = pr[e]; i1 = e; }
    int i2 = -1; float v2 = -1.f;
    #pragma unroll
    for (int e = 0; e < EE; ++e) if (e != i1 && pr[e] > v2) { v2 = pr[e]; i2 = e; }

    float wsum = v1 + v2;
    float w1n = v1 / wsum, w2n = v2 / wsum;

    float a[EE * LL];
    #pragma unroll
    for (int el = 0; el < EE * LL; ++el) a[el] = wsA[(size_t)el * NB + row];

    #pragma unroll
    for (int l = 0; l < LL; ++l)
        out[(size_t)row * LL + l] = w1n * a[i1 * LL + l] + w2n * a[i2 * LL + l];

    #pragma unroll
    for (int e = 0; e < EE; ++e)
        #pragma unroll
        for (int l = 0; l < LL; ++l)
            out[(size_t)NB * (LL + EE) + (size_t)row * (EE * LL) + e * LL + l] =
                (e == i1 || e == i2) ? a[e * LL + l] : 0.f;
}

extern "C" void kernel_launch(void* const* d_in, const int* in_sizes, int n_in,
                              void* d_out, int out_size, void* d_ws, size_t ws_size,
                              hipStream_t stream)
{
    const float* hs = (const float*)d_in[0];
    const float* W1 = (const float*)d_in[1];
    const float* b1 = (const float*)d_in[2];
    const float* W2 = (const float*)d_in[3];
    const float* b2 = (const float*)d_in[4];
    const float* We = (const float*)d_in[5];
    const float* be = (const float*)d_in[6];
    float* out = (float*)d_out;

    char* ws = (char*)d_ws;
    f16*   bHi = (f16*)(ws);                 // 1179648 B
    f16*   bLo = (f16*)(ws + 1179648);       // 1179648 B
    float* wsP = (float*)(ws + 2359296);     // 2621440 B
    float* wsA = (float*)(ws + 4980736);     // 327680 B  -> total 5308416 B

    hipLaunchKernelGGL(k0_fused, dim3(144 + NB / 4), dim3(256), 0, stream,
                       W1, hs, We, be, bHi, bLo, wsA);
    hipLaunchKernelGGL(k1_gemm, dim3(512), dim3(256), 0, stream, hs, bHi, bLo, b1, W2, wsP);
    hipLaunchKernelGGL(k2_epilogue, dim3(NB / 256), dim3(256), 0, stream, wsP, wsA, b2, out);
}